// Round 5
// baseline (35.576 us; speedup 1.0000x reference)
//
#include <hip/hip_runtime.h>
#include <math.h>

#define D 128
// level 0: R=24 rows/graph (nodes); level 1: R=40 rows/graph (line graph)
// out layout (floats): s_h@0, s_t@32768, s_h_line@65536, s_t_line@98304
//
// ws layout (in _Float16 units):
//   W fp16: Wh@0, Wt@16384, Whl@32768, Wtl@49152          (128 KB)
//   G @ 65536:  Gh0@+0 (6144x256), Gt0@+1572864 (6144x256),
//               Gh1@+3145728 (10240x256), Gt1@+5767168 (10240x256)
//   total 65536 + 8388608 halfs = 16.9 MB  (< 32 MiB ws)

typedef float f32x4 __attribute__((ext_vector_type(4)));
typedef _Float16 f16x8 __attribute__((ext_vector_type(8)));

union PK4 { _Float16 h[4]; ushort4 v; };

__device__ __forceinline__ f16x8 cvt8(float4 a, float4 b) {
    f16x8 r;
    r[0] = (_Float16)a.x; r[1] = (_Float16)a.y; r[2] = (_Float16)a.z; r[3] = (_Float16)a.w;
    r[4] = (_Float16)b.x; r[5] = (_Float16)b.y; r[6] = (_Float16)b.z; r[7] = (_Float16)b.w;
    return r;
}

__device__ __forceinline__ float tanh_fast(float x) {
    float cx = fminf(fmaxf(x, -15.f), 15.f);
    float t = __expf(2.f * cx);
    return __fdividef(t - 1.f, t + 1.f);
}

// ---- prep: convert 4 W matrices (128x128 f32) to fp16 in ws ----
__global__ __launch_bounds__(256) void prep_w(
    const float* __restrict__ w0, const float* __restrict__ w1,
    const float* __restrict__ w2, const float* __restrict__ w3,
    _Float16* __restrict__ W16)
{
    int t = blockIdx.x * 256 + threadIdx.x;      // 0..16383 float4s
    int m = t >> 12;
    int q = t & 4095;
    const float* src = (m == 0) ? w0 : (m == 1) ? w1 : (m == 2) ? w2 : w3;
    float4 v = *reinterpret_cast<const float4*>(src + q * 4);
    PK4 pk;
    pk.h[0] = (_Float16)v.x; pk.h[1] = (_Float16)v.y;
    pk.h[2] = (_Float16)v.z; pk.h[3] = (_Float16)v.w;
    *reinterpret_cast<ushort4*>(&W16[m * 16384 + q * 4]) = pk.v;
}

// ---- GEMM: G = x @ [WA^T | WB^T] + [bA | bB], fp16 out ----
// 256 blocks x 256 thr; block = 128 rows x 256 cols; wave w owns rows w*32..w*32+31.
// MFMA rule (validated r1/r2/r4): mfma(P,Q): lane(lm,lq) reg r = dot(P_row[lq*4+r], Q_row[lm]);
// fragments loaded row = lane&15, k = (lane>>4)*8 + e.
__global__ __launch_bounds__(256) void gemm_G(
    const float* __restrict__ xnh, const float* __restrict__ xnt,
    const float* __restrict__ xlh, const float* __restrict__ xlt,
    const float* __restrict__ bh, const float* __restrict__ bt,
    const float* __restrict__ bhl, const float* __restrict__ btl,
    const _Float16* __restrict__ W16, _Float16* __restrict__ G)
{
    const int idx = blockIdx.x;
    const float *X, *bA, *bB;
    const _Float16 *WA, *WB;
    _Float16* Gd;
    int r0;
    if (idx < 48)       { X = xnh; WA = W16;         WB = W16 + 16384; bA = bh;  bB = bt;  Gd = G;           r0 = idx * 128; }
    else if (idx < 96)  { X = xnt; WA = W16 + 16384; WB = W16;         bA = bt;  bB = bh;  Gd = G + 1572864; r0 = (idx - 48) * 128; }
    else if (idx < 176) { X = xlh; WA = W16 + 32768; WB = W16 + 49152; bA = bhl; bB = btl; Gd = G + 3145728; r0 = (idx - 96) * 128; }
    else                { X = xlt; WA = W16 + 49152; WB = W16 + 32768; bA = btl; bB = bhl; Gd = G + 5767168; r0 = (idx - 176) * 128; }

    const int w = threadIdx.x >> 6, l = threadIdx.x & 63;
    const int lm = l & 15, lq = l >> 4;
    const int rw = r0 + w * 32;

    f32x4 acc[2][16];
#pragma unroll
    for (int ti = 0; ti < 2; ++ti)
#pragma unroll
        for (int c = 0; c < 16; ++c) acc[ti][c] = (f32x4){0.f, 0.f, 0.f, 0.f};

#pragma unroll
    for (int ks = 0; ks < 4; ++ks) {
        const int k0 = ks * 32 + lq * 8;
        f16x8 q[2];
#pragma unroll
        for (int ti = 0; ti < 2; ++ti) {
            const float* xr = X + (rw + ti * 16 + lm) * D + k0;
            float4 va = *reinterpret_cast<const float4*>(xr);
            float4 vb = *reinterpret_cast<const float4*>(xr + 4);
            q[ti] = cvt8(va, vb);
        }
#pragma unroll
        for (int ctl = 0; ctl < 16; ++ctl) {
            const _Float16* wp = (ctl < 8) ? (WA + (ctl * 16 + lm) * D + k0)
                                           : (WB + ((ctl - 8) * 16 + lm) * D + k0);
            f16x8 P = *reinterpret_cast<const f16x8*>(wp);
            acc[0][ctl] = __builtin_amdgcn_mfma_f32_16x16x32_f16(P, q[0], acc[0][ctl], 0, 0, 0);
            acc[1][ctl] = __builtin_amdgcn_mfma_f32_16x16x32_f16(P, q[1], acc[1][ctl], 0, 0, 0);
        }
    }

    // epilogue: lane holds G[i = rw+ti*16+lm][n = ctl*16 + lq*4 + r]
#pragma unroll
    for (int ctl = 0; ctl < 16; ++ctl) {
        const int nc = ctl * 16 + lq * 4;
        const float* bp = (ctl < 8) ? (bA + nc) : (bB + nc - 128);
        float4 b4 = *reinterpret_cast<const float4*>(bp);
#pragma unroll
        for (int ti = 0; ti < 2; ++ti) {
            const int i = rw + ti * 16 + lm;
            PK4 pk;
            pk.h[0] = (_Float16)(acc[ti][ctl][0] + b4.x);
            pk.h[1] = (_Float16)(acc[ti][ctl][1] + b4.y);
            pk.h[2] = (_Float16)(acc[ti][ctl][2] + b4.z);
            pk.h[3] = (_Float16)(acc[ti][ctl][3] + b4.w);
            *reinterpret_cast<ushort4*>(&Gd[i * 256 + nc]) = pk.v;
        }
    }
}

// ---- attention: alpha = tanh(G_h @ G_t^T) block-diag, reductions, softmax, outputs ----
template <int LEVEL>
__device__ __forceinline__ void attn_body(
    int g, const float* __restrict__ xh, const float* __restrict__ xt,
    const _Float16* __restrict__ Gh, const _Float16* __restrict__ Gt,
    float* __restrict__ osh, float* __restrict__ ost,
    float* colpart, float* bh_s, float* pt_s, float* ph_s)
{
    constexpr int R = (LEVEL == 0) ? 24 : 40;
    constexpr int TM = (LEVEL == 0) ? 2 : 3;
    constexpr float invR = 1.f / (float)R;

    const int tid = threadIdx.x;
    const int w = tid >> 6, l = tid & 63;
    const int lm = l & 15, lq = l >> 4;
    const int base = g * R;

    // wave w owns i-tile w:  i = w*16 + lq*4 + r,  j = tj*16 + lm
    float cs[3] = {0.f, 0.f, 0.f};
    if (w < TM) {
        const f16x8 z8 = {0, 0, 0, 0, 0, 0, 0, 0};
        f32x4 acc2[TM];
#pragma unroll
        for (int tj = 0; tj < TM; ++tj) acc2[tj] = (f32x4){0.f, 0.f, 0.f, 0.f};

        const int ri = w * 16 + lm;
        const bool vi = (ri < R);
        const int ric = vi ? ri : (R - 1);
        int rjc[TM];
        bool vj[TM];
#pragma unroll
        for (int tj = 0; tj < TM; ++tj) {
            int rj = tj * 16 + lm;
            vj[tj] = (rj < R);
            rjc[tj] = vj[tj] ? rj : (R - 1);
        }
#pragma unroll
        for (int ksa = 0; ksa < 8; ++ksa) {
            const int k0 = ksa * 32 + lq * 8;
            f16x8 Ah = *reinterpret_cast<const f16x8*>(&Gh[(base + ric) * 256 + k0]);
            Ah = vi ? Ah : z8;
#pragma unroll
            for (int tj = 0; tj < TM; ++tj) {
                f16x8 Bh = *reinterpret_cast<const f16x8*>(&Gt[(base + rjc[tj]) * 256 + k0]);
                Bh = vj[tj] ? Bh : z8;
                acc2[tj] = __builtin_amdgcn_mfma_f32_16x16x32_f16(Ah, Bh, acc2[tj], 0, 0, 0);
            }
        }

        float at[TM][4];
#pragma unroll
        for (int tj = 0; tj < TM; ++tj)
#pragma unroll
            for (int r = 0; r < 4; ++r) at[tj][r] = tanh_fast(acc2[tj][r]);

        // row sums over j -> bh_s[i]; padded entries are tanh(0)=0
#pragma unroll
        for (int r = 0; r < 4; ++r) {
            float s = 0.f;
#pragma unroll
            for (int tj = 0; tj < TM; ++tj) s += at[tj][r];
            s += __shfl_xor(s, 1, 64);
            s += __shfl_xor(s, 2, 64);
            s += __shfl_xor(s, 4, 64);
            s += __shfl_xor(s, 8, 64);
            if (lm == 0) bh_s[w * 16 + lq * 4 + r] = s;
        }
        // col partial sums over this i-tile -> cs[tj]
#pragma unroll
        for (int tj = 0; tj < TM; ++tj) {
            float s = 0.f;
#pragma unroll
            for (int r = 0; r < 4; ++r) s += at[tj][r];
            s += __shfl_xor(s, 16, 64);
            s += __shfl_xor(s, 32, 64);
            cs[tj] = s;
        }
    }
#pragma unroll
    for (int tj = 0; tj < 3; ++tj)
        if (lq == 0) colpart[w * 48 + tj * 16 + lm] = (tj < TM) ? cs[tj] : 0.f;
    __syncthreads();

    // softmaxes: wave0 -> p_t (col sums / R), wave1 -> p_h (row sums / R)
    if (w == 0) {
        float v = (l < 48) ? (colpart[l] + colpart[48 + l] + colpart[96 + l] + colpart[144 + l]) : 0.f;
        float val = (l < R) ? v * invR : -INFINITY;
        float m = val;
        for (int o = 32; o; o >>= 1) m = fmaxf(m, __shfl_xor(m, o, 64));
        float e = (l < R) ? __expf(val - m) : 0.f;
        float s = e;
        for (int o = 32; o; o >>= 1) s += __shfl_xor(s, o, 64);
        if (l < R) pt_s[l] = e / s;
    } else if (w == 1) {
        float val = (l < R) ? bh_s[l] * invR : -INFINITY;
        float m = val;
        for (int o = 32; o; o >>= 1) m = fmaxf(m, __shfl_xor(m, o, 64));
        float e = (l < R) ? __expf(val - m) : 0.f;
        float s = e;
        for (int o = 32; o; o >>= 1) s += __shfl_xor(s, o, 64);
        if (l < R) ph_s[l] = e / s;
    }
    __syncthreads();

    // outputs: threads 0..127 -> s_t col c; 128..255 -> s_h col c
    if (tid < 128) {
        int c = tid;
        float a = 0.f;
        for (int j = 0; j < R; ++j) a += pt_s[j] * xt[(base + j) * D + c];
        ost[g * D + c] = a;
    } else {
        int c = tid - 128;
        float a = 0.f;
        for (int i = 0; i < R; ++i) a += ph_s[i] * xh[(base + i) * D + c];
        osh[g * D + c] = a;
    }
}

__global__ __launch_bounds__(256) void attn_kernel(
    const float* __restrict__ xnh, const float* __restrict__ xnt,
    const float* __restrict__ xlh, const float* __restrict__ xlt,
    const _Float16* __restrict__ G, float* __restrict__ out)
{
    __shared__ float colpart[192], bh_s[48], pt_s[48], ph_s[48];
    int idx = blockIdx.x;
    if (idx < 256)
        attn_body<0>(idx, xnh, xnt, G, G + 1572864, out + 0, out + 32768,
                     colpart, bh_s, pt_s, ph_s);
    else
        attn_body<1>(idx - 256, xlh, xlt, G + 3145728, G + 5767168, out + 65536, out + 98304,
                     colpart, bh_s, pt_s, ph_s);
}

extern "C" void kernel_launch(void* const* d_in, const int* in_sizes, int n_in,
                              void* d_out, int out_size, void* d_ws, size_t ws_size,
                              hipStream_t stream) {
    const float* xnh   = (const float*)d_in[0];
    const float* xnt   = (const float*)d_in[1];
    const float* xlh   = (const float*)d_in[2];
    const float* xlt   = (const float*)d_in[3];
    const float* Wh_w  = (const float*)d_in[4];
    const float* Wh_b  = (const float*)d_in[5];
    const float* Wt_w  = (const float*)d_in[6];
    const float* Wt_b  = (const float*)d_in[7];
    const float* Whl_w = (const float*)d_in[8];
    const float* Whl_b = (const float*)d_in[9];
    const float* Wtl_w = (const float*)d_in[10];
    const float* Wtl_b = (const float*)d_in[11];

    _Float16* W16 = (_Float16*)d_ws;
    _Float16* G   = W16 + 65536;
    float* out = (float*)d_out;

    prep_w<<<64, 256, 0, stream>>>(Wh_w, Wt_w, Whl_w, Wtl_w, W16);
    gemm_G<<<256, 256, 0, stream>>>(xnh, xnt, xlh, xlt,
                                    Wh_b, Wt_b, Whl_b, Wtl_b, W16, G);
    attn_kernel<<<512, 256, 0, stream>>>(xnh, xnt, xlh, xlt, G, out);
}